// Round 5
// baseline (195.345 us; speedup 1.0000x reference)
//
#include <hip/hip_runtime.h>
#include <hip/hip_bf16.h>

// B=2, T=2048, C=1024, H=16, D=64
// convx(X) -> convt(W_attn) -> qkv_gemm -> attn_v5 (paired causal tiles) ->
// convt(W_proj) -> proj_gemm

typedef __attribute__((ext_vector_type(8))) short bf16x8;
typedef __attribute__((ext_vector_type(4))) short bf16x4;
typedef __attribute__((ext_vector_type(4))) float f32x4;

__device__ __forceinline__ short f2bs(float f) {
    union { __hip_bfloat16 h; short s; } u;
    u.h = __float2bfloat16(f);
    return u.s;
}

#define GLOAD_LDS16(gp, lp)                                                        \
    __builtin_amdgcn_global_load_lds((const __attribute__((address_space(1))) void*)(gp), \
                                     (__attribute__((address_space(3))) void*)(lp), 16, 0, 0)

// ---------------------------------------------------------------------------
// convx: X f32 [4096*1024] -> bf16.
// ---------------------------------------------------------------------------
__global__ __launch_bounds__(256) void convx(
    const float* __restrict__ X, short* __restrict__ Xb)
{
    const size_t i = ((size_t)blockIdx.x * 256 + threadIdx.x) * 8;
    float4 a = *(const float4*)(X + i);
    float4 b = *(const float4*)(X + i + 4);
    bf16x8 s;
    s[0] = f2bs(a.x); s[1] = f2bs(a.y); s[2] = f2bs(a.z); s[3] = f2bs(a.w);
    s[4] = f2bs(b.x); s[5] = f2bs(b.y); s[6] = f2bs(b.z); s[7] = f2bs(b.w);
    *(bf16x8*)(Xb + i) = s;
}

// ---------------------------------------------------------------------------
// convert + transpose: W f32 [K][N] -> Wt bf16 [N][K].
// ---------------------------------------------------------------------------
__global__ __launch_bounds__(256) void convt(
    const float* __restrict__ W, short* __restrict__ Wt, int K, int N)
{
    __shared__ short t[64 * 72];
    const int tid = threadIdx.x;
    const int n0 = blockIdx.x * 64, k0 = blockIdx.y * 64;
    #pragma unroll
    for (int i = 0; i < 4; i++) {
        int k = (tid >> 4) + i * 16;
        int n = (tid & 15) * 4;
        float4 v = *(const float4*)(W + (size_t)(k0 + k) * N + n0 + n);
        t[(n + 0) * 72 + k] = f2bs(v.x);
        t[(n + 1) * 72 + k] = f2bs(v.y);
        t[(n + 2) * 72 + k] = f2bs(v.z);
        t[(n + 3) * 72 + k] = f2bs(v.w);
    }
    __syncthreads();
    #pragma unroll
    for (int i = 0; i < 2; i++) {
        int n  = (tid >> 3) + i * 32;
        int kc = (tid & 7) * 8;
        bf16x8 v = *(const bf16x8*)&t[n * 72 + kc];
        *(bf16x8*)(Wt + (size_t)(n0 + n) * K + k0 + kc) = v;
    }
}

// ---------------------------------------------------------------------------
// Kernel 1: QKV GEMM.  Xb bf16 x Wt bf16 (+bias) -> Q (pre-scaled), K, V^T
// ---------------------------------------------------------------------------
__global__ __launch_bounds__(256) void qkv_gemm(
    const short* __restrict__ Xb, const short* __restrict__ Wt,
    const float* __restrict__ bias,
    short* __restrict__ Qw, short* __restrict__ Kw, short* __restrict__ Vt)
{
    __shared__ short Al[128 * 64];
    __shared__ short Bl[128 * 64];
    const int tid  = threadIdx.x;
    const int lane = tid & 63;
    const int wid  = tid >> 6;
    const int wm = wid >> 1, wn = wid & 1;
    const int g = lane >> 4, cc = lane & 15;
    const int m0 = blockIdx.y * 128, n0 = blockIdx.x * 128;

    f32x4 acc[4][4];
    const f32x4 z4 = {0.f, 0.f, 0.f, 0.f};
    #pragma unroll
    for (int i = 0; i < 4; i++)
        #pragma unroll
        for (int j = 0; j < 4; j++) acc[i][j] = z4;

    for (int k0 = 0; k0 < 1024; k0 += 64) {
        #pragma unroll
        for (int i = 0; i < 4; i++) {
            int chunk = (wid * 4 + i) * 64 + lane;
            int row = chunk >> 3, c = chunk & 7;
            GLOAD_LDS16(Xb + (size_t)(m0 + row) * 1024 + k0 + c * 8, &Al[chunk * 8]);
        }
        #pragma unroll
        for (int i = 0; i < 4; i++) {
            int chunk = (wid * 4 + i) * 64 + lane;
            int row = chunk >> 3, c = chunk & 7;
            GLOAD_LDS16(Wt + (size_t)(n0 + row) * 1024 + k0 + c * 8, &Bl[chunk * 8]);
        }
        __syncthreads();

        #pragma unroll
        for (int kk = 0; kk < 2; kk++) {
            bf16x8 af[4], bfv[4];
            #pragma unroll
            for (int m = 0; m < 4; m++)
                af[m] = *(const bf16x8*)&Al[(wm * 64 + m * 16 + cc) * 64 + kk * 32 + g * 8];
            #pragma unroll
            for (int n = 0; n < 4; n++)
                bfv[n] = *(const bf16x8*)&Bl[(wn * 64 + n * 16 + cc) * 64 + kk * 32 + g * 8];
            #pragma unroll
            for (int m = 0; m < 4; m++)
                #pragma unroll
                for (int n = 0; n < 4; n++)
                    acc[m][n] = __builtin_amdgcn_mfma_f32_16x16x32_bf16(af[m], bfv[n], acc[m][n], 0, 0, 0);
        }
        __syncthreads();
    }

    const float QSCALE = 0.04508422976f;   // log2(e)/sqrt(1024)
    #pragma unroll
    for (int n = 0; n < 4; n++) {
        int col = n0 + wn * 64 + n * 16 + cc;
        int which = col >> 10;
        int ci = col & 1023;
        int h = ci >> 6, d = ci & 63;
        float bv = bias[col];
        #pragma unroll
        for (int m = 0; m < 4; m++) {
            #pragma unroll
            for (int r = 0; r < 4; r++) {
                int row = m0 + wm * 64 + m * 16 + g * 4 + r;
                int b = row >> 11, t = row & 2047;
                int bh = b * 16 + h;
                float v = acc[m][n][r] + bv;
                if (which == 0)      Qw[((size_t)bh * 2048 + t) * 64 + d] = f2bs(v * QSCALE);
                else if (which == 1) Kw[((size_t)bh * 2048 + t) * 64 + d] = f2bs(v);
                else                 Vt[((size_t)bh * 64 + d) * 2048 + t] = f2bs(v);
            }
        }
    }
}

// ---------------------------------------------------------------------------
// Kernel 2: causal flash attention with PAIRED 16-row q-tiles.
// Pair p: tile A = p (rows p*16..), tile B = 127-p. One shared KV stream;
// tile A drops out when its causal extent ends. Work = 65 steps for ALL
// 2048 blocks -> steady occupancy, no tail decay.
// ---------------------------------------------------------------------------
__global__ __launch_bounds__(64) void attn_v5(
    const short* __restrict__ Qw, const short* __restrict__ Kw,
    const short* __restrict__ Vt, short* __restrict__ Aout)
{
    __shared__ short P[2 * 16 * 40];
    const int lane = threadIdx.x;
    const int g = lane >> 4, cc = lane & 15;
    const int bid = blockIdx.x;
    const int bh = bid & 31;              // XCD = bh % 8 -> per-head L2 locality
    const int p  = bid >> 5;              // pair index 0..63
    const int rA = p * 16, rB = (127 - p) * 16;
    const int stepsA = (p + 2) >> 1;
    const int stepsB = (129 - p) >> 1;
    const int b = bh >> 4, h = bh & 15;
    const short* Qb = Qw + (size_t)bh * 2048 * 64;
    const short* Kb = Kw + (size_t)bh * 2048 * 64;
    const short* Vb = Vt + (size_t)bh * 64 * 2048;

    // Q as B-operand: col = q = cc, k = d = ds*32 + g*8 + j
    bf16x8 qA[2], qB[2];
    #pragma unroll
    for (int ds = 0; ds < 2; ds++) {
        qA[ds] = *(const bf16x8*)(Qb + (rA + cc) * 64 + ds * 32 + g * 8);
        qB[ds] = *(const bf16x8*)(Qb + (rB + cc) * 64 + ds * 32 + g * 8);
    }

    const f32x4 z4 = {0.f, 0.f, 0.f, 0.f};
    f32x4 oA[4], oB[4];
    #pragma unroll
    for (int ch = 0; ch < 4; ch++) { oA[ch] = z4; oB[ch] = z4; }
    float mA = -1e30f, lA = 0.f, mB = -1e30f, lB = 0.f;

    bf16x8 kf[4], vf[4];                  // kf[kvc*2+ds]; vf[ch]
    #pragma unroll
    for (int kvc = 0; kvc < 2; kvc++)
        #pragma unroll
        for (int ds = 0; ds < 2; ds++)
            kf[kvc * 2 + ds] = *(const bf16x8*)(Kb + (kvc * 16 + cc) * 64 + ds * 32 + g * 8);
    #pragma unroll
    for (int ch = 0; ch < 4; ch++)
        vf[ch] = *(const bf16x8*)(Vb + (ch * 16 + cc) * 2048 + g * 8);

    for (int st = 0; st < stepsB; st++) {
        const int kv0 = st * 32;
        const int kvn = (st + 1 < stepsB) ? kv0 + 32 : kv0;
        const bool procA = (st < stepsA);
        bf16x8 kn[4], vn[4];
        #pragma unroll
        for (int kvc = 0; kvc < 2; kvc++)
            #pragma unroll
            for (int ds = 0; ds < 2; ds++)
                kn[kvc * 2 + ds] = *(const bf16x8*)(Kb + (kvn + kvc * 16 + cc) * 64 + ds * 32 + g * 8);
        #pragma unroll
        for (int ch = 0; ch < 4; ch++)
            vn[ch] = *(const bf16x8*)(Vb + (ch * 16 + cc) * 2048 + kvn + g * 8);

        // S^T tiles: rows kv = g*4+r (+16 for kvc=1), cols q = cc
        f32x4 sB[2], sA[2];
        __builtin_amdgcn_s_setprio(1);
        #pragma unroll
        for (int kvc = 0; kvc < 2; kvc++) {
            sB[kvc] = z4;
            #pragma unroll
            for (int ds = 0; ds < 2; ds++)
                sB[kvc] = __builtin_amdgcn_mfma_f32_16x16x32_bf16(
                    kf[kvc * 2 + ds], qB[ds], sB[kvc], 0, 0, 0);
        }
        if (procA) {
            #pragma unroll
            for (int kvc = 0; kvc < 2; kvc++) {
                sA[kvc] = z4;
                #pragma unroll
                for (int ds = 0; ds < 2; ds++)
                    sA[kvc] = __builtin_amdgcn_mfma_f32_16x16x32_bf16(
                        kf[kvc * 2 + ds], qA[ds], sA[kvc], 0, 0, 0);
            }
        }
        __builtin_amdgcn_s_setprio(0);

        // ---- softmax tile B ----
        {
            const int qq = rB + cc;
            const bool masked = (st == stepsB - 1);
            float sv[8];
            #pragma unroll
            for (int kvc = 0; kvc < 2; kvc++)
                #pragma unroll
                for (int r = 0; r < 4; r++) {
                    float v = sB[kvc][r];
                    if (masked) {
                        int kv = kv0 + kvc * 16 + g * 4 + r;
                        v = (kv <= qq) ? v : -1e30f;
                    }
                    sv[kvc * 4 + r] = v;
                }
            float mx = fmaxf(fmaxf(fmaxf(sv[0], sv[1]), fmaxf(sv[2], sv[3])),
                             fmaxf(fmaxf(sv[4], sv[5]), fmaxf(sv[6], sv[7])));
            mx = fmaxf(mx, __shfl_xor(mx, 16));
            mx = fmaxf(mx, __shfl_xor(mx, 32));
            if (__any(mx > mB + 6.0f)) {
                float mn = fmaxf(mB, mx);
                float a = exp2f(mB - mn);
                #pragma unroll
                for (int ch = 0; ch < 4; ch++)
                    #pragma unroll
                    for (int r = 0; r < 4; r++) oB[ch][r] *= a;
                lB *= a;
                mB = mn;
            }
            float pv[8], rs = 0.f;
            #pragma unroll
            for (int i = 0; i < 8; i++) { pv[i] = exp2f(sv[i] - mB); rs += pv[i]; }
            rs += __shfl_xor(rs, 16);
            rs += __shfl_xor(rs, 32);
            lB += rs;
            bf16x4 w0, w1;
            #pragma unroll
            for (int r = 0; r < 4; r++) { w0[r] = f2bs(pv[r]); w1[r] = f2bs(pv[4 + r]); }
            *(bf16x4*)&P[cc * 40 + g * 4]      = w0;
            *(bf16x4*)&P[cc * 40 + 16 + g * 4] = w1;
        }
        // ---- softmax tile A ----
        if (procA) {
            const int qq = rA + cc;
            const bool masked = (st == stepsA - 1);
            float sv[8];
            #pragma unroll
            for (int kvc = 0; kvc < 2; kvc++)
                #pragma unroll
                for (int r = 0; r < 4; r++) {
                    float v = sA[kvc][r];
                    if (masked) {
                        int kv = kv0 + kvc * 16 + g * 4 + r;
                        v = (kv <= qq) ? v : -1e30f;
                    }
                    sv[kvc * 4 + r] = v;
                }
            float mx = fmaxf(fmaxf(fmaxf(sv[0], sv[1]), fmaxf(sv[2], sv[3])),
                             fmaxf(fmaxf(sv[4], sv[5]), fmaxf(sv[6], sv[7])));
            mx = fmaxf(mx, __shfl_xor(mx, 16));
            mx = fmaxf(mx, __shfl_xor(mx, 32));
            if (__any(mx > mA + 6.0f)) {
                float mn = fmaxf(mA, mx);
                float a = exp2f(mA - mn);
                #pragma unroll
                for (int ch = 0; ch < 4; ch++)
                    #pragma unroll
                    for (int r = 0; r < 4; r++) oA[ch][r] *= a;
                lA *= a;
                mA = mn;
            }
            float pv[8], rs = 0.f;
            #pragma unroll
            for (int i = 0; i < 8; i++) { pv[i] = exp2f(sv[i] - mA); rs += pv[i]; }
            rs += __shfl_xor(rs, 16);
            rs += __shfl_xor(rs, 32);
            lA += rs;
            bf16x4 w0, w1;
            #pragma unroll
            for (int r = 0; r < 4; r++) { w0[r] = f2bs(pv[r]); w1[r] = f2bs(pv[4 + r]); }
            *(bf16x4*)&P[640 + cc * 40 + g * 4]      = w0;
            *(bf16x4*)&P[640 + cc * 40 + 16 + g * 4] = w1;
        }

        asm volatile("s_waitcnt lgkmcnt(0)" ::: "memory");
        bf16x8 paB = *(const bf16x8*)&P[cc * 40 + g * 8];

        __builtin_amdgcn_s_setprio(1);
        #pragma unroll
        for (int ch = 0; ch < 4; ch++)
            oB[ch] = __builtin_amdgcn_mfma_f32_16x16x32_bf16(vf[ch], paB, oB[ch], 0, 0, 0);
        if (procA) {
            bf16x8 paA = *(const bf16x8*)&P[640 + cc * 40 + g * 8];
            #pragma unroll
            for (int ch = 0; ch < 4; ch++)
                oA[ch] = __builtin_amdgcn_mfma_f32_16x16x32_bf16(vf[ch], paA, oA[ch], 0, 0, 0);
        }
        __builtin_amdgcn_s_setprio(0);

        #pragma unroll
        for (int i = 0; i < 4; i++) { kf[i] = kn[i]; vf[i] = vn[i]; }
    }

    // epilogue: O^T cols q=cc -> t; rows d = ch*16 + g*4 + r
    {
        float rl = 1.0f / lB;
        const int t = rB + cc;
        #pragma unroll
        for (int ch = 0; ch < 4; ch++) {
            bf16x4 ov;
            #pragma unroll
            for (int r = 0; r < 4; r++) ov[r] = f2bs(oB[ch][r] * rl);
            *(bf16x4*)(Aout + ((size_t)b * 2048 + t) * 1024 + h * 64 + ch * 16 + g * 4) = ov;
        }
    }
    {
        float rl = 1.0f / lA;
        const int t = rA + cc;
        #pragma unroll
        for (int ch = 0; ch < 4; ch++) {
            bf16x4 ov;
            #pragma unroll
            for (int r = 0; r < 4; r++) ov[r] = f2bs(oA[ch][r] * rl);
            *(bf16x4*)(Aout + ((size_t)b * 2048 + t) * 1024 + h * 64 + ch * 16 + g * 4) = ov;
        }
    }
}

// ---------------------------------------------------------------------------
// Kernel 3: projection. 128x64 tile (512 blocks = 2/CU).
// ---------------------------------------------------------------------------
__global__ __launch_bounds__(256) void proj_gemm(
    const short* __restrict__ A, const short* __restrict__ Wt,
    const float* __restrict__ bias, float* __restrict__ Out)
{
    __shared__ short Al[128 * 64];
    __shared__ short Bl[64 * 64];
    const int tid  = threadIdx.x;
    const int lane = tid & 63;
    const int wid  = tid >> 6;
    const int wm = wid >> 1, wn = wid & 1;
    const int g = lane >> 4, cc = lane & 15;
    const int m0 = blockIdx.y * 128, n0 = blockIdx.x * 64;

    f32x4 acc[4][2];
    const f32x4 z4 = {0.f, 0.f, 0.f, 0.f};
    #pragma unroll
    for (int i = 0; i < 4; i++)
        #pragma unroll
        for (int j = 0; j < 2; j++) acc[i][j] = z4;

    for (int k0 = 0; k0 < 1024; k0 += 64) {
        #pragma unroll
        for (int i = 0; i < 4; i++) {
            int chunk = (wid * 4 + i) * 64 + lane;
            int row = chunk >> 3, c = chunk & 7;
            GLOAD_LDS16(A + (size_t)(m0 + row) * 1024 + k0 + c * 8, &Al[chunk * 8]);
        }
        #pragma unroll
        for (int i = 0; i < 2; i++) {
            int chunk = (wid * 2 + i) * 64 + lane;
            int row = chunk >> 3, c = chunk & 7;
            GLOAD_LDS16(Wt + (size_t)(n0 + row) * 1024 + k0 + c * 8, &Bl[chunk * 8]);
        }
        __syncthreads();

        #pragma unroll
        for (int kk = 0; kk < 2; kk++) {
            bf16x8 af[4], bfv[2];
            #pragma unroll
            for (int m = 0; m < 4; m++)
                af[m] = *(const bf16x8*)&Al[(wm * 64 + m * 16 + cc) * 64 + kk * 32 + g * 8];
            #pragma unroll
            for (int n = 0; n < 2; n++)
                bfv[n] = *(const bf16x8*)&Bl[(wn * 32 + n * 16 + cc) * 64 + kk * 32 + g * 8];
            #pragma unroll
            for (int m = 0; m < 4; m++)
                #pragma unroll
                for (int n = 0; n < 2; n++)
                    acc[m][n] = __builtin_amdgcn_mfma_f32_16x16x32_bf16(af[m], bfv[n], acc[m][n], 0, 0, 0);
        }
        __syncthreads();
    }

    #pragma unroll
    for (int n = 0; n < 2; n++) {
        int col = n0 + wn * 32 + n * 16 + cc;
        float bv = bias[col];
        #pragma unroll
        for (int m = 0; m < 4; m++) {
            #pragma unroll
            for (int r = 0; r < 4; r++) {
                int row = m0 + wm * 64 + m * 16 + g * 4 + r;
                Out[(size_t)row * 1024 + col] = acc[m][n][r] + bv;
            }
        }
    }
}

// ---------------------------------------------------------------------------
extern "C" void kernel_launch(void* const* d_in, const int* in_sizes, int n_in,
                              void* d_out, int out_size, void* d_ws, size_t ws_size,
                              hipStream_t stream)
{
    const float* x      = (const float*)d_in[0];
    const float* W_attn = (const float*)d_in[1];
    const float* b_attn = (const float*)d_in[2];
    const float* W_proj = (const float*)d_in[3];
    const float* b_proj = (const float*)d_in[4];
    float* out = (float*)d_out;

    const size_t SZ = (size_t)4096 * 1024;
    short* R1 = (short*)d_ws;                  // Wt_attn, later Aout
    short* Qw = R1 + SZ;                       // later Wt_proj
    short* Kw = Qw + SZ;
    short* Vt = Kw + SZ;

    short* Wt_attn = R1;
    short* Aout    = R1;
    short* Wt_proj = Qw;
    short* Xb      = (short*)d_out;            // d_out as bf16 scratch until proj

    convx<<<dim3(2048), 256, 0, stream>>>(x, Xb);
    convt<<<dim3(48, 16), 256, 0, stream>>>(W_attn, Wt_attn, 1024, 3072);
    qkv_gemm<<<dim3(24, 32), 256, 0, stream>>>(Xb, Wt_attn, b_attn, Qw, Kw, Vt);
    attn_v5<<<dim3(2048), 64, 0, stream>>>(Qw, Kw, Vt, Aout);
    convt<<<dim3(16, 16), 256, 0, stream>>>(W_proj, Wt_proj, 1024, 1024);
    proj_gemm<<<dim3(16, 32), 256, 0, stream>>>(Aout, Wt_proj, b_proj, out);
}

// Round 6
// 174.398 us; speedup vs baseline: 1.1201x; 1.1201x over previous
//
#include <hip/hip_runtime.h>
#include <hip/hip_bf16.h>

// B=2, T=2048, C=1024, H=16, D=64
// convx(X) -> convt(W_attn) -> qkv_gemm (Q pre-scaled, V sigma-permuted) ->
// attn_v6 (no-LDS, gated softmax) -> convt(W_proj) -> proj_gemm

typedef __attribute__((ext_vector_type(8))) short bf16x8;
typedef __attribute__((ext_vector_type(4))) short bf16x4;
typedef __attribute__((ext_vector_type(4))) float f32x4;

__device__ __forceinline__ short f2bs(float f) {
    union { __hip_bfloat16 h; short s; } u;
    u.h = __float2bfloat16(f);
    return u.s;
}

#define GLOAD_LDS16(gp, lp)                                                        \
    __builtin_amdgcn_global_load_lds((const __attribute__((address_space(1))) void*)(gp), \
                                     (__attribute__((address_space(3))) void*)(lp), 16, 0, 0)

// ---------------------------------------------------------------------------
// convx: X f32 [4096*1024] -> bf16.
// ---------------------------------------------------------------------------
__global__ __launch_bounds__(256) void convx(
    const float* __restrict__ X, short* __restrict__ Xb)
{
    const size_t i = ((size_t)blockIdx.x * 256 + threadIdx.x) * 8;
    float4 a = *(const float4*)(X + i);
    float4 b = *(const float4*)(X + i + 4);
    bf16x8 s;
    s[0] = f2bs(a.x); s[1] = f2bs(a.y); s[2] = f2bs(a.z); s[3] = f2bs(a.w);
    s[4] = f2bs(b.x); s[5] = f2bs(b.y); s[6] = f2bs(b.z); s[7] = f2bs(b.w);
    *(bf16x8*)(Xb + i) = s;
}

// ---------------------------------------------------------------------------
// convert + transpose: W f32 [K][N] -> Wt bf16 [N][K].
// ---------------------------------------------------------------------------
__global__ __launch_bounds__(256) void convt(
    const float* __restrict__ W, short* __restrict__ Wt, int K, int N)
{
    __shared__ short t[64 * 72];
    const int tid = threadIdx.x;
    const int n0 = blockIdx.x * 64, k0 = blockIdx.y * 64;
    #pragma unroll
    for (int i = 0; i < 4; i++) {
        int k = (tid >> 4) + i * 16;
        int n = (tid & 15) * 4;
        float4 v = *(const float4*)(W + (size_t)(k0 + k) * N + n0 + n);
        t[(n + 0) * 72 + k] = f2bs(v.x);
        t[(n + 1) * 72 + k] = f2bs(v.y);
        t[(n + 2) * 72 + k] = f2bs(v.z);
        t[(n + 3) * 72 + k] = f2bs(v.w);
    }
    __syncthreads();
    #pragma unroll
    for (int i = 0; i < 2; i++) {
        int n  = (tid >> 3) + i * 32;
        int kc = (tid & 7) * 8;
        bf16x8 v = *(const bf16x8*)&t[n * 72 + kc];
        *(bf16x8*)(Wt + (size_t)(n0 + n) * K + k0 + kc) = v;
    }
}

// ---------------------------------------------------------------------------
// Kernel 1: QKV GEMM.  Xb bf16 x Wt bf16 (+bias) -> Q (pre-scaled), K, V^T
// V^T columns sigma-permuted within each 32-col block so attn's PV B-operand
// is lane-local (no LDS transpose in attn).
// ---------------------------------------------------------------------------
__global__ __launch_bounds__(256) void qkv_gemm(
    const short* __restrict__ Xb, const short* __restrict__ Wt,
    const float* __restrict__ bias,
    short* __restrict__ Qw, short* __restrict__ Kw, short* __restrict__ Vt)
{
    __shared__ short Al[128 * 64];
    __shared__ short Bl[128 * 64];
    const int tid  = threadIdx.x;
    const int lane = tid & 63;
    const int wid  = tid >> 6;
    const int wm = wid >> 1, wn = wid & 1;
    const int g = lane >> 4, cc = lane & 15;
    const int m0 = blockIdx.y * 128, n0 = blockIdx.x * 128;

    f32x4 acc[4][4];
    const f32x4 z4 = {0.f, 0.f, 0.f, 0.f};
    #pragma unroll
    for (int i = 0; i < 4; i++)
        #pragma unroll
        for (int j = 0; j < 4; j++) acc[i][j] = z4;

    for (int k0 = 0; k0 < 1024; k0 += 64) {
        #pragma unroll
        for (int i = 0; i < 4; i++) {
            int chunk = (wid * 4 + i) * 64 + lane;
            int row = chunk >> 3, c = chunk & 7;
            GLOAD_LDS16(Xb + (size_t)(m0 + row) * 1024 + k0 + c * 8, &Al[chunk * 8]);
        }
        #pragma unroll
        for (int i = 0; i < 4; i++) {
            int chunk = (wid * 4 + i) * 64 + lane;
            int row = chunk >> 3, c = chunk & 7;
            GLOAD_LDS16(Wt + (size_t)(n0 + row) * 1024 + k0 + c * 8, &Bl[chunk * 8]);
        }
        __syncthreads();

        #pragma unroll
        for (int kk = 0; kk < 2; kk++) {
            bf16x8 af[4], bfv[4];
            #pragma unroll
            for (int m = 0; m < 4; m++)
                af[m] = *(const bf16x8*)&Al[(wm * 64 + m * 16 + cc) * 64 + kk * 32 + g * 8];
            #pragma unroll
            for (int n = 0; n < 4; n++)
                bfv[n] = *(const bf16x8*)&Bl[(wn * 64 + n * 16 + cc) * 64 + kk * 32 + g * 8];
            #pragma unroll
            for (int m = 0; m < 4; m++)
                #pragma unroll
                for (int n = 0; n < 4; n++)
                    acc[m][n] = __builtin_amdgcn_mfma_f32_16x16x32_bf16(af[m], bfv[n], acc[m][n], 0, 0, 0);
        }
        __syncthreads();
    }

    const float QSCALE = 0.04508422976f;   // log2(e)/sqrt(1024)
    #pragma unroll
    for (int n = 0; n < 4; n++) {
        int col = n0 + wn * 64 + n * 16 + cc;
        int which = col >> 10;
        int ci = col & 1023;
        int h = ci >> 6, d = ci & 63;
        float bv = bias[col];
        #pragma unroll
        for (int m = 0; m < 4; m++) {
            #pragma unroll
            for (int r = 0; r < 4; r++) {
                int row = m0 + wm * 64 + m * 16 + g * 4 + r;
                int b = row >> 11, t = row & 2047;
                int bh = b * 16 + h;
                float v = acc[m][n][r] + bv;
                if (which == 0)      Qw[((size_t)bh * 2048 + t) * 64 + d] = f2bs(v * QSCALE);
                else if (which == 1) Kw[((size_t)bh * 2048 + t) * 64 + d] = f2bs(v);
                else {
                    // sigma^{-1} permute within 32-col block:
                    // p = ((t>>2)&3)*8 + ((t>>4)&1)*4 + (t&3)
                    int tp = (t & ~31) | (((t >> 2) & 3) * 8 + ((t >> 4) & 1) * 4 + (t & 3));
                    Vt[((size_t)bh * 64 + d) * 2048 + tp] = f2bs(v);
                }
            }
        }
    }
}

// ---------------------------------------------------------------------------
// Kernel 2: causal flash attention v6. 1 wave per 32 q-rows.
// No LDS. S^T = mfma(K,Q); gated defer-max (no shuffles common case);
// per-lane deferred l-sum; PV B-operand = lane-local p (V sigma-permuted).
// K/V double-buffered in registers via manual unroll-by-2.
// ---------------------------------------------------------------------------
#define ATTN_STEP(KF, VF, KN, VN, KVN, PRE, MSK, KV0)                             \
  {                                                                               \
    if (PRE) {                                                                    \
      _Pragma("unroll") for (int kvc = 0; kvc < 2; kvc++)                         \
      _Pragma("unroll") for (int ds = 0; ds < 2; ds++)                            \
        KN[kvc * 2 + ds] = *(const bf16x8*)(Kb + ((KVN) + kvc * 16 + cc) * 64 + ds * 32 + g * 8); \
      _Pragma("unroll") for (int ch = 0; ch < 4; ch++)                            \
        VN[ch] = *(const bf16x8*)(Vb + (ch * 16 + cc) * 2048 + (KVN) + g * 8);     \
    }                                                                             \
    f32x4 s_[2][2];                                                               \
    _Pragma("unroll") for (int qf = 0; qf < 2; qf++)                              \
    _Pragma("unroll") for (int kvc = 0; kvc < 2; kvc++) {                         \
      s_[qf][kvc] = z4;                                                           \
      _Pragma("unroll") for (int ds = 0; ds < 2; ds++)                            \
        s_[qf][kvc] = __builtin_amdgcn_mfma_f32_16x16x32_bf16(                    \
            KF[kvc * 2 + ds], qfr[qf][ds], s_[qf][kvc], 0, 0, 0);                 \
    }                                                                             \
    bf16x8 pb_[2];                                                                \
    _Pragma("unroll") for (int qf = 0; qf < 2; qf++) {                            \
      float sv[8];                                                                \
      _Pragma("unroll") for (int kvc = 0; kvc < 2; kvc++)                         \
      _Pragma("unroll") for (int r = 0; r < 4; r++) {                             \
        float v = s_[qf][kvc][r];                                                 \
        if (MSK) {                                                                \
          int kv = (KV0) + kvc * 16 + g * 4 + r;                                  \
          v = (kv <= q0 + qf * 16 + cc) ? v : -1e30f;                             \
        }                                                                         \
        sv[kvc * 4 + r] = v;                                                      \
      }                                                                           \
      float lm = fmaxf(fmaxf(fmaxf(sv[0], sv[1]), fmaxf(sv[2], sv[3])),           \
                       fmaxf(fmaxf(sv[4], sv[5]), fmaxf(sv[6], sv[7])));          \
      if (__any(lm > m_r[qf] + 6.0f)) {                                           \
        float mx = lm;                                                            \
        mx = fmaxf(mx, __shfl_xor(mx, 16));                                       \
        mx = fmaxf(mx, __shfl_xor(mx, 32));                                       \
        float mn = fmaxf(m_r[qf], mx);                                            \
        float a = exp2f(m_r[qf] - mn);                                            \
        _Pragma("unroll") for (int ch = 0; ch < 4; ch++)                          \
        _Pragma("unroll") for (int r = 0; r < 4; r++) o[qf][ch][r] *= a;          \
        l_l[qf] *= a;                                                             \
        m_r[qf] = mn;                                                             \
      }                                                                           \
      float rs = 0.f;                                                             \
      _Pragma("unroll") for (int i = 0; i < 8; i++) {                             \
        float p = exp2f(sv[i] - m_r[qf]);                                         \
        pb_[qf][i] = f2bs(p);                                                     \
        rs += p;                                                                  \
      }                                                                           \
      l_l[qf] += rs;                                                              \
    }                                                                             \
    _Pragma("unroll") for (int ch = 0; ch < 4; ch++) {                            \
      o[0][ch] = __builtin_amdgcn_mfma_f32_16x16x32_bf16(VF[ch], pb_[0], o[0][ch], 0, 0, 0); \
      o[1][ch] = __builtin_amdgcn_mfma_f32_16x16x32_bf16(VF[ch], pb_[1], o[1][ch], 0, 0, 0); \
    }                                                                             \
  }

__global__ __launch_bounds__(64) void attn_v6(
    const short* __restrict__ Qw, const short* __restrict__ Kw,
    const short* __restrict__ Vt, short* __restrict__ Aout)
{
    const int lane = threadIdx.x;
    const int g = lane >> 4, cc = lane & 15;
    const int bid = blockIdx.x;
    const int qt = 63 - (bid >> 5);       // longest tiles first
    const int bh = bid & 31;              // XCD = bh % 8 -> per-head L2 locality
    const int q0 = qt * 32;
    const int b = bh >> 4, h = bh & 15;
    const short* Qb = Qw + (size_t)bh * 2048 * 64;
    const short* Kb = Kw + (size_t)bh * 2048 * 64;
    const short* Vb = Vt + (size_t)bh * 64 * 2048;

    // Q as B-operand: col = q, k = d
    bf16x8 qfr[2][2];
    #pragma unroll
    for (int qf = 0; qf < 2; qf++)
        #pragma unroll
        for (int ds = 0; ds < 2; ds++)
            qfr[qf][ds] = *(const bf16x8*)(Qb + (q0 + qf * 16 + cc) * 64 + ds * 32 + g * 8);

    const f32x4 z4 = {0.f, 0.f, 0.f, 0.f};
    f32x4 o[2][4];
    #pragma unroll
    for (int qf = 0; qf < 2; qf++)
        #pragma unroll
        for (int ch = 0; ch < 4; ch++) o[qf][ch] = z4;
    float m_r[2] = {-1e30f, -1e30f};
    float l_l[2] = {0.f, 0.f};

    bf16x8 kA[4], vA[4], kB[4], vB[4];
    #pragma unroll
    for (int kvc = 0; kvc < 2; kvc++)
        #pragma unroll
        for (int ds = 0; ds < 2; ds++)
            kA[kvc * 2 + ds] = *(const bf16x8*)(Kb + (kvc * 16 + cc) * 64 + ds * 32 + g * 8);
    #pragma unroll
    for (int ch = 0; ch < 4; ch++)
        vA[ch] = *(const bf16x8*)(Vb + (ch * 16 + cc) * 2048 + g * 8);

    int st = 0;
    while (st + 2 <= qt) {
        ATTN_STEP(kA, vA, kB, vB, (st + 1) * 32, 1, 0, 0);
        ATTN_STEP(kB, vB, kA, vA, (st + 2) * 32, 1, 0, 0);
        st += 2;
    }
    if (st < qt) {
        ATTN_STEP(kA, vA, kB, vB, (st + 1) * 32, 1, 0, 0);
        ATTN_STEP(kB, vB, kB, vB, 0, 0, 1, qt * 32);
    } else {
        ATTN_STEP(kA, vA, kA, vA, 0, 0, 1, qt * 32);
    }

    // epilogue: reduce l across g-lanes, write O^T cols q=cc
    #pragma unroll
    for (int qf = 0; qf < 2; qf++) {
        float lt = l_l[qf];
        lt += __shfl_xor(lt, 16);
        lt += __shfl_xor(lt, 32);
        float rl = 1.0f / lt;
        const int t = q0 + qf * 16 + cc;
        #pragma unroll
        for (int ch = 0; ch < 4; ch++) {
            bf16x4 ov;
            #pragma unroll
            for (int r = 0; r < 4; r++) ov[r] = f2bs(o[qf][ch][r] * rl);
            *(bf16x4*)(Aout + ((size_t)b * 2048 + t) * 1024 + h * 64 + ch * 16 + g * 4) = ov;
        }
    }
}

// ---------------------------------------------------------------------------
// Kernel 3: projection. 128x64 tile (512 blocks = 2/CU).
// ---------------------------------------------------------------------------
__global__ __launch_bounds__(256) void proj_gemm(
    const short* __restrict__ A, const short* __restrict__ Wt,
    const float* __restrict__ bias, float* __restrict__ Out)
{
    __shared__ short Al[128 * 64];
    __shared__ short Bl[64 * 64];
    const int tid  = threadIdx.x;
    const int lane = tid & 63;
    const int wid  = tid >> 6;
    const int wm = wid >> 1, wn = wid & 1;
    const int g = lane >> 4, cc = lane & 15;
    const int m0 = blockIdx.y * 128, n0 = blockIdx.x * 64;

    f32x4 acc[4][2];
    const f32x4 z4 = {0.f, 0.f, 0.f, 0.f};
    #pragma unroll
    for (int i = 0; i < 4; i++)
        #pragma unroll
        for (int j = 0; j < 2; j++) acc[i][j] = z4;

    for (int k0 = 0; k0 < 1024; k0 += 64) {
        #pragma unroll
        for (int i = 0; i < 4; i++) {
            int chunk = (wid * 4 + i) * 64 + lane;
            int row = chunk >> 3, c = chunk & 7;
            GLOAD_LDS16(A + (size_t)(m0 + row) * 1024 + k0 + c * 8, &Al[chunk * 8]);
        }
        #pragma unroll
        for (int i = 0; i < 2; i++) {
            int chunk = (wid * 2 + i) * 64 + lane;
            int row = chunk >> 3, c = chunk & 7;
            GLOAD_LDS16(Wt + (size_t)(n0 + row) * 1024 + k0 + c * 8, &Bl[chunk * 8]);
        }
        __syncthreads();

        #pragma unroll
        for (int kk = 0; kk < 2; kk++) {
            bf16x8 af[4], bfv[2];
            #pragma unroll
            for (int m = 0; m < 4; m++)
                af[m] = *(const bf16x8*)&Al[(wm * 64 + m * 16 + cc) * 64 + kk * 32 + g * 8];
            #pragma unroll
            for (int n = 0; n < 2; n++)
                bfv[n] = *(const bf16x8*)&Bl[(wn * 32 + n * 16 + cc) * 64 + kk * 32 + g * 8];
            #pragma unroll
            for (int m = 0; m < 4; m++)
                #pragma unroll
                for (int n = 0; n < 2; n++)
                    acc[m][n] = __builtin_amdgcn_mfma_f32_16x16x32_bf16(af[m], bfv[n], acc[m][n], 0, 0, 0);
        }
        __syncthreads();
    }

    #pragma unroll
    for (int n = 0; n < 2; n++) {
        int col = n0 + wn * 32 + n * 16 + cc;
        float bv = bias[col];
        #pragma unroll
        for (int m = 0; m < 4; m++) {
            #pragma unroll
            for (int r = 0; r < 4; r++) {
                int row = m0 + wm * 64 + m * 16 + g * 4 + r;
                Out[(size_t)row * 1024 + col] = acc[m][n][r] + bv;
            }
        }
    }
}

// ---------------------------------------------------------------------------
extern "C" void kernel_launch(void* const* d_in, const int* in_sizes, int n_in,
                              void* d_out, int out_size, void* d_ws, size_t ws_size,
                              hipStream_t stream)
{
    const float* x      = (const float*)d_in[0];
    const float* W_attn = (const float*)d_in[1];
    const float* b_attn = (const float*)d_in[2];
    const float* W_proj = (const float*)d_in[3];
    const float* b_proj = (const float*)d_in[4];
    float* out = (float*)d_out;

    const size_t SZ = (size_t)4096 * 1024;
    short* R1 = (short*)d_ws;                  // Wt_attn, later Aout
    short* Qw = R1 + SZ;                       // later Wt_proj
    short* Kw = Qw + SZ;
    short* Vt = Kw + SZ;

    short* Wt_attn = R1;
    short* Aout    = R1;
    short* Wt_proj = Qw;
    short* Xb      = (short*)d_out;            // d_out as bf16 scratch until proj

    convx<<<dim3(2048), 256, 0, stream>>>(x, Xb);
    convt<<<dim3(48, 16), 256, 0, stream>>>(W_attn, Wt_attn, 1024, 3072);
    qkv_gemm<<<dim3(24, 32), 256, 0, stream>>>(Xb, Wt_attn, b_attn, Qw, Kw, Vt);
    attn_v6<<<dim3(2048), 64, 0, stream>>>(Qw, Kw, Vt, Aout);
    convt<<<dim3(16, 16), 256, 0, stream>>>(W_proj, Wt_proj, 1024, 1024);
    proj_gemm<<<dim3(16, 32), 256, 0, stream>>>(Aout, Wt_proj, b_proj, out);
}

// Round 7
// 158.401 us; speedup vs baseline: 1.2332x; 1.1010x over previous
//
#include <hip/hip_runtime.h>
#include <hip/hip_bf16.h>

// B=2, T=2048, C=1024, H=16, D=64
// convx(X) -> convt(W_attn) -> qkv_gemm (256x192 8-wave counted-vmcnt) ->
// attn_v6 (no-LDS) -> convt(W_proj) -> proj_gemm

typedef __attribute__((ext_vector_type(8))) short bf16x8;
typedef __attribute__((ext_vector_type(4))) short bf16x4;
typedef __attribute__((ext_vector_type(4))) float f32x4;

__device__ __forceinline__ short f2bs(float f) {
    union { __hip_bfloat16 h; short s; } u;
    u.h = __float2bfloat16(f);
    return u.s;
}

#define GLOAD_LDS16(gp, lp)                                                        \
    __builtin_amdgcn_global_load_lds((const __attribute__((address_space(1))) void*)(gp), \
                                     (__attribute__((address_space(3))) void*)(lp), 16, 0, 0)

// ---------------------------------------------------------------------------
// convx: X f32 [4096*1024] -> bf16.
// ---------------------------------------------------------------------------
__global__ __launch_bounds__(256) void convx(
    const float* __restrict__ X, short* __restrict__ Xb)
{
    const size_t i = ((size_t)blockIdx.x * 256 + threadIdx.x) * 8;
    float4 a = *(const float4*)(X + i);
    float4 b = *(const float4*)(X + i + 4);
    bf16x8 s;
    s[0] = f2bs(a.x); s[1] = f2bs(a.y); s[2] = f2bs(a.z); s[3] = f2bs(a.w);
    s[4] = f2bs(b.x); s[5] = f2bs(b.y); s[6] = f2bs(b.z); s[7] = f2bs(b.w);
    *(bf16x8*)(Xb + i) = s;
}

// ---------------------------------------------------------------------------
// convert + transpose: W f32 [K][N] -> Wt bf16 [N][K].
// ---------------------------------------------------------------------------
__global__ __launch_bounds__(256) void convt(
    const float* __restrict__ W, short* __restrict__ Wt, int K, int N)
{
    __shared__ short t[64 * 72];
    const int tid = threadIdx.x;
    const int n0 = blockIdx.x * 64, k0 = blockIdx.y * 64;
    #pragma unroll
    for (int i = 0; i < 4; i++) {
        int k = (tid >> 4) + i * 16;
        int n = (tid & 15) * 4;
        float4 v = *(const float4*)(W + (size_t)(k0 + k) * N + n0 + n);
        t[(n + 0) * 72 + k] = f2bs(v.x);
        t[(n + 1) * 72 + k] = f2bs(v.y);
        t[(n + 2) * 72 + k] = f2bs(v.z);
        t[(n + 3) * 72 + k] = f2bs(v.w);
    }
    __syncthreads();
    #pragma unroll
    for (int i = 0; i < 2; i++) {
        int n  = (tid >> 3) + i * 32;
        int kc = (tid & 7) * 8;
        bf16x8 v = *(const bf16x8*)&t[n * 72 + kc];
        *(bf16x8*)(Wt + (size_t)(n0 + n) * K + k0 + kc) = v;
    }
}

// ---------------------------------------------------------------------------
// Kernel 1: QKV GEMM, 256x192 tile, BK=64, 8 waves (2Mx4N), double-buffered
// LDS with counted vmcnt (T3/T4), XOR-swizzled reads (T2), setprio (T5).
// Xb bf16 [4096][1024] x Wt bf16 [3072][1024] -> Q (pre-scaled), K, V^T(sigma)
// ---------------------------------------------------------------------------
__global__ __launch_bounds__(512) void qkv_gemm(
    const short* __restrict__ Xb, const short* __restrict__ Wt,
    const float* __restrict__ bias,
    short* __restrict__ Qw, short* __restrict__ Kw, short* __restrict__ Vt)
{
    __shared__ short Alds[2][256 * 64];   // [dbuf][row][64] (swizzled cols)
    __shared__ short Blds[2][192 * 64];
    const int tid  = threadIdx.x;
    const int lane = tid & 63;
    const int wid  = tid >> 6;            // 0..7
    const int wm = wid >> 2, wn = wid & 3;
    const int g = lane >> 4, cc = lane & 15;
    const int sw = cc & 7;                // read-side swizzle key

    // XCD-bijective swizzle: 256 blocks, 8 XCDs, 32 consecutive wgid each.
    // wgid>>4 = n-block (2 per XCD -> B panel L2-resident), wgid&15 = m-block.
    const int bid  = blockIdx.x;
    const int wgid = (bid & 7) * 32 + (bid >> 3);
    const int n0 = (wgid >> 4) * 192;
    const int m0 = (wgid & 15) * 256;

    f32x4 acc[8][3];
    const f32x4 z4 = {0.f, 0.f, 0.f, 0.f};
    #pragma unroll
    for (int i = 0; i < 8; i++)
        #pragma unroll
        for (int j = 0; j < 3; j++) acc[i][j] = z4;

    // stage K-tile t into buffer buf: 7 gload_lds per thread (4 A + 3 B).
    // LDS dest linear; global source chunk = phys_chunk ^ (row&7)  [rule 21]
    auto STAGE = [&](int t, int buf) {
        const int k0 = t * 64;
        #pragma unroll
        for (int j = 0; j < 4; j++) {
            int c = j * 512 + wid * 64 + lane;        // 0..2047
            int row = c >> 3, sch = (c & 7) ^ (row & 7);
            GLOAD_LDS16(Xb + (size_t)(m0 + row) * 1024 + k0 + sch * 8,
                        &Alds[buf][c * 8]);
        }
        #pragma unroll
        for (int j = 0; j < 3; j++) {
            int c = j * 512 + wid * 64 + lane;        // 0..1535
            int row = c >> 3, sch = (c & 7) ^ (row & 7);
            GLOAD_LDS16(Wt + (size_t)(n0 + row) * 1024 + k0 + sch * 8,
                        &Blds[buf][c * 8]);
        }
    };

    STAGE(0, 0);
    STAGE(1, 1);
    asm volatile("s_waitcnt vmcnt(7)" ::: "memory");   // tile 0 landed
    asm volatile("s_barrier" ::: "memory");

    const int NT = 16;                    // K/64
    for (int t = 0; t < NT; t++) {
        const short* Ab = Alds[t & 1];
        const short* Bb = Blds[t & 1];

        bf16x8 bfr[3][2];
        #pragma unroll
        for (int nf = 0; nf < 3; nf++)
            #pragma unroll
            for (int kk = 0; kk < 2; kk++)
                bfr[nf][kk] = *(const bf16x8*)&Bb[(wn * 48 + nf * 16 + cc) * 64 +
                                                  ((kk * 4 + g) ^ sw) * 8];
        // phase 1: A-frags mf 0..3
        {
            bf16x8 af[4][2];
            #pragma unroll
            for (int mf = 0; mf < 4; mf++)
                #pragma unroll
                for (int kk = 0; kk < 2; kk++)
                    af[mf][kk] = *(const bf16x8*)&Ab[(wm * 128 + mf * 16 + cc) * 64 +
                                                     ((kk * 4 + g) ^ sw) * 8];
            __builtin_amdgcn_s_setprio(1);
            #pragma unroll
            for (int mf = 0; mf < 4; mf++)
                #pragma unroll
                for (int nf = 0; nf < 3; nf++)
                    #pragma unroll
                    for (int kk = 0; kk < 2; kk++)
                        acc[mf][nf] = __builtin_amdgcn_mfma_f32_16x16x32_bf16(
                            af[mf][kk], bfr[nf][kk], acc[mf][nf], 0, 0, 0);
            __builtin_amdgcn_s_setprio(0);
        }
        // phase 2: A-frags mf 4..7
        {
            bf16x8 af[4][2];
            #pragma unroll
            for (int mf = 0; mf < 4; mf++)
                #pragma unroll
                for (int kk = 0; kk < 2; kk++)
                    af[mf][kk] = *(const bf16x8*)&Ab[(wm * 128 + (mf + 4) * 16 + cc) * 64 +
                                                     ((kk * 4 + g) ^ sw) * 8];
            __builtin_amdgcn_s_setprio(1);
            #pragma unroll
            for (int mf = 0; mf < 4; mf++)
                #pragma unroll
                for (int nf = 0; nf < 3; nf++)
                    #pragma unroll
                    for (int kk = 0; kk < 2; kk++)
                        acc[mf + 4][nf] = __builtin_amdgcn_mfma_f32_16x16x32_bf16(
                            af[mf][kk], bfr[nf][kk], acc[mf + 4][nf], 0, 0, 0);
            __builtin_amdgcn_s_setprio(0);
        }

        asm volatile("s_barrier" ::: "memory");        // all reads of this buf done
        if (t + 2 < NT) {
            STAGE(t + 2, t & 1);                       // overwrite consumed buf
            asm volatile("s_waitcnt vmcnt(7)" ::: "memory");  // tile t+1 landed
            asm volatile("s_barrier" ::: "memory");
        } else if (t + 1 < NT) {
            asm volatile("s_waitcnt vmcnt(0)" ::: "memory");
            asm volatile("s_barrier" ::: "memory");
        }
    }

    const float QSCALE = 0.04508422976f;   // log2(e)/sqrt(1024)
    #pragma unroll
    for (int nf = 0; nf < 3; nf++) {
        int col = n0 + wn * 48 + nf * 16 + cc;
        int which = col >> 10;
        int ci = col & 1023;
        int h = ci >> 6, d = ci & 63;
        float bv = bias[col];
        #pragma unroll
        for (int mf = 0; mf < 8; mf++) {
            #pragma unroll
            for (int r = 0; r < 4; r++) {
                int row = m0 + wm * 128 + mf * 16 + g * 4 + r;
                int b = row >> 11, tt = row & 2047;
                int bh = b * 16 + h;
                float v = acc[mf][nf][r] + bv;
                if (which == 0)      Qw[((size_t)bh * 2048 + tt) * 64 + d] = f2bs(v * QSCALE);
                else if (which == 1) Kw[((size_t)bh * 2048 + tt) * 64 + d] = f2bs(v);
                else {
                    int tp = (tt & ~31) | (((tt >> 2) & 3) * 8 + ((tt >> 4) & 1) * 4 + (tt & 3));
                    Vt[((size_t)bh * 64 + d) * 2048 + tp] = f2bs(v);
                }
            }
        }
    }
}

// ---------------------------------------------------------------------------
// Kernel 2: causal flash attention v6. 1 wave per 32 q-rows. No LDS.
// ---------------------------------------------------------------------------
#define ATTN_STEP(KF, VF, KN, VN, KVN, PRE, MSK, KV0)                             \
  {                                                                               \
    if (PRE) {                                                                    \
      _Pragma("unroll") for (int kvc = 0; kvc < 2; kvc++)                         \
      _Pragma("unroll") for (int ds = 0; ds < 2; ds++)                            \
        KN[kvc * 2 + ds] = *(const bf16x8*)(Kb + ((KVN) + kvc * 16 + cc) * 64 + ds * 32 + g * 8); \
      _Pragma("unroll") for (int ch = 0; ch < 4; ch++)                            \
        VN[ch] = *(const bf16x8*)(Vb + (ch * 16 + cc) * 2048 + (KVN) + g * 8);     \
    }                                                                             \
    f32x4 s_[2][2];                                                               \
    _Pragma("unroll") for (int qf = 0; qf < 2; qf++)                              \
    _Pragma("unroll") for (int kvc = 0; kvc < 2; kvc++) {                         \
      s_[qf][kvc] = z4;                                                           \
      _Pragma("unroll") for (int ds = 0; ds < 2; ds++)                            \
        s_[qf][kvc] = __builtin_amdgcn_mfma_f32_16x16x32_bf16(                    \
            KF[kvc * 2 + ds], qfr[qf][ds], s_[qf][kvc], 0, 0, 0);                 \
    }                                                                             \
    bf16x8 pb_[2];                                                                \
    _Pragma("unroll") for (int qf = 0; qf < 2; qf++) {                            \
      float sv[8];                                                                \
      _Pragma("unroll") for (int kvc = 0; kvc < 2; kvc++)                         \
      _Pragma("unroll") for (int r = 0; r < 4; r++) {                             \
        float v = s_[qf][kvc][r];                                                 \
        if (MSK) {                                                                \
          int kv = (KV0) + kvc * 16 + g * 4 + r;                                  \
          v = (kv <= q0 + qf * 16 + cc) ? v : -1e30f;                             \
        }                                                                         \
        sv[kvc * 4 + r] = v;                                                      \
      }                                                                           \
      float lm = fmaxf(fmaxf(fmaxf(sv[0], sv[1]), fmaxf(sv[2], sv[3])),           \
                       fmaxf(fmaxf(sv[4], sv[5]), fmaxf(sv[6], sv[7])));          \
      if (__any(lm > m_r[qf] + 6.0f)) {                                           \
        float mx = lm;                                                            \
        mx = fmaxf(mx, __shfl_xor(mx, 16));                                       \
        mx = fmaxf(mx, __shfl_xor(mx, 32));                                       \
        float mn = fmaxf(m_r[qf], mx);                                            \
        float a = exp2f(m_r[qf] - mn);                                            \
        _Pragma("unroll") for (int ch = 0; ch < 4; ch++)                          \
        _Pragma("unroll") for (int r = 0; r < 4; r++) o[qf][ch][r] *= a;          \
        l_l[qf] *= a;                                                             \
        m_r[qf] = mn;                                                             \
      }                                                                           \
      float rs = 0.f;                                                             \
      _Pragma("unroll") for (int i = 0; i < 8; i++) {                             \
        float p = exp2f(sv[i] - m_r[qf]);                                         \
        pb_[qf][i] = f2bs(p);                                                     \
        rs += p;                                                                  \
      }                                                                           \
      l_l[qf] += rs;                                                              \
    }                                                                             \
    _Pragma("unroll") for (int ch = 0; ch < 4; ch++) {                            \
      o[0][ch] = __builtin_amdgcn_mfma_f32_16x16x32_bf16(VF[ch], pb_[0], o[0][ch], 0, 0, 0); \
      o[1][ch] = __builtin_amdgcn_mfma_f32_16x16x32_bf16(VF[ch], pb_[1], o[1][ch], 0, 0, 0); \
    }                                                                             \
  }

__global__ __launch_bounds__(64) void attn_v6(
    const short* __restrict__ Qw, const short* __restrict__ Kw,
    const short* __restrict__ Vt, short* __restrict__ Aout)
{
    const int lane = threadIdx.x;
    const int g = lane >> 4, cc = lane & 15;
    const int bid = blockIdx.x;
    const int qt = 63 - (bid >> 5);       // longest tiles first
    const int bh = bid & 31;              // XCD = bh % 8 -> per-head L2 locality
    const int q0 = qt * 32;
    const int b = bh >> 4, h = bh & 15;
    const short* Qb = Qw + (size_t)bh * 2048 * 64;
    const short* Kb = Kw + (size_t)bh * 2048 * 64;
    const short* Vb = Vt + (size_t)bh * 64 * 2048;

    bf16x8 qfr[2][2];
    #pragma unroll
    for (int qf = 0; qf < 2; qf++)
        #pragma unroll
        for (int ds = 0; ds < 2; ds++)
            qfr[qf][ds] = *(const bf16x8*)(Qb + (q0 + qf * 16 + cc) * 64 + ds * 32 + g * 8);

    const f32x4 z4 = {0.f, 0.f, 0.f, 0.f};
    f32x4 o[2][4];
    #pragma unroll
    for (int qf = 0; qf < 2; qf++)
        #pragma unroll
        for (int ch = 0; ch < 4; ch++) o[qf][ch] = z4;
    float m_r[2] = {-1e30f, -1e30f};
    float l_l[2] = {0.f, 0.f};

    bf16x8 kA[4], vA[4], kB[4], vB[4];
    #pragma unroll
    for (int kvc = 0; kvc < 2; kvc++)
        #pragma unroll
        for (int ds = 0; ds < 2; ds++)
            kA[kvc * 2 + ds] = *(const bf16x8*)(Kb + (kvc * 16 + cc) * 64 + ds * 32 + g * 8);
    #pragma unroll
    for (int ch = 0; ch < 4; ch++)
        vA[ch] = *(const bf16x8*)(Vb + (ch * 16 + cc) * 2048 + g * 8);

    int st = 0;
    while (st + 2 <= qt) {
        ATTN_STEP(kA, vA, kB, vB, (st + 1) * 32, 1, 0, 0);
        ATTN_STEP(kB, vB, kA, vA, (st + 2) * 32, 1, 0, 0);
        st += 2;
    }
    if (st < qt) {
        ATTN_STEP(kA, vA, kB, vB, (st + 1) * 32, 1, 0, 0);
        ATTN_STEP(kB, vB, kB, vB, 0, 0, 1, qt * 32);
    } else {
        ATTN_STEP(kA, vA, kA, vA, 0, 0, 1, qt * 32);
    }

    #pragma unroll
    for (int qf = 0; qf < 2; qf++) {
        float lt = l_l[qf];
        lt += __shfl_xor(lt, 16);
        lt += __shfl_xor(lt, 32);
        float rl = 1.0f / lt;
        const int t = q0 + qf * 16 + cc;
        #pragma unroll
        for (int ch = 0; ch < 4; ch++) {
            bf16x4 ov;
            #pragma unroll
            for (int r = 0; r < 4; r++) ov[r] = f2bs(o[qf][ch][r] * rl);
            *(bf16x4*)(Aout + ((size_t)b * 2048 + t) * 1024 + h * 64 + ch * 16 + g * 4) = ov;
        }
    }
}

// ---------------------------------------------------------------------------
// Kernel 3: projection. 128x64 tile (512 blocks = 2/CU).
// ---------------------------------------------------------------------------
__global__ __launch_bounds__(256) void proj_gemm(
    const short* __restrict__ A, const short* __restrict__ Wt,
    const float* __restrict__ bias, float* __restrict__ Out)
{
    __shared__ short Al[128 * 64];
    __shared__ short Bl[64 * 64];
    const int tid  = threadIdx.x;
    const int lane = tid & 63;
    const int wid  = tid >> 6;
    const int wm = wid >> 1, wn = wid & 1;
    const int g = lane >> 4, cc = lane & 15;
    const int m0 = blockIdx.y * 128, n0 = blockIdx.x * 64;

    f32x4 acc[4][2];
    const f32x4 z4 = {0.f, 0.f, 0.f, 0.f};
    #pragma unroll
    for (int i = 0; i < 4; i++)
        #pragma unroll
        for (int j = 0; j < 2; j++) acc[i][j] = z4;

    for (int k0 = 0; k0 < 1024; k0 += 64) {
        #pragma unroll
        for (int i = 0; i < 4; i++) {
            int chunk = (wid * 4 + i) * 64 + lane;
            int row = chunk >> 3, c = chunk & 7;
            GLOAD_LDS16(A + (size_t)(m0 + row) * 1024 + k0 + c * 8, &Al[chunk * 8]);
        }
        #pragma unroll
        for (int i = 0; i < 2; i++) {
            int chunk = (wid * 2 + i) * 64 + lane;
            int row = chunk >> 3, c = chunk & 7;
            GLOAD_LDS16(Wt + (size_t)(n0 + row) * 1024 + k0 + c * 8, &Bl[chunk * 8]);
        }
        __syncthreads();

        #pragma unroll
        for (int kk = 0; kk < 2; kk++) {
            bf16x8 af[4], bfv[2];
            #pragma unroll
            for (int m = 0; m < 4; m++)
                af[m] = *(const bf16x8*)&Al[(wm * 64 + m * 16 + cc) * 64 + kk * 32 + g * 8];
            #pragma unroll
            for (int n = 0; n < 2; n++)
                bfv[n] = *(const bf16x8*)&Bl[(wn * 32 + n * 16 + cc) * 64 + kk * 32 + g * 8];
            #pragma unroll
            for (int m = 0; m < 4; m++)
                #pragma unroll
                for (int n = 0; n < 2; n++)
                    acc[m][n] = __builtin_amdgcn_mfma_f32_16x16x32_bf16(af[m], bfv[n], acc[m][n], 0, 0, 0);
        }
        __syncthreads();
    }

    #pragma unroll
    for (int n = 0; n < 2; n++) {
        int col = n0 + wn * 32 + n * 16 + cc;
        float bv = bias[col];
        #pragma unroll
        for (int m = 0; m < 4; m++) {
            #pragma unroll
            for (int r = 0; r < 4; r++) {
                int row = m0 + wm * 64 + m * 16 + g * 4 + r;
                Out[(size_t)row * 1024 + col] = acc[m][n][r] + bv;
            }
        }
    }
}

// ---------------------------------------------------------------------------
extern "C" void kernel_launch(void* const* d_in, const int* in_sizes, int n_in,
                              void* d_out, int out_size, void* d_ws, size_t ws_size,
                              hipStream_t stream)
{
    const float* x      = (const float*)d_in[0];
    const float* W_attn = (const float*)d_in[1];
    const float* b_attn = (const float*)d_in[2];
    const float* W_proj = (const float*)d_in[3];
    const float* b_proj = (const float*)d_in[4];
    float* out = (float*)d_out;

    const size_t SZ = (size_t)4096 * 1024;
    short* R1 = (short*)d_ws;                  // Wt_attn, later Aout
    short* Qw = R1 + SZ;                       // later Wt_proj
    short* Kw = Qw + SZ;
    short* Vt = Kw + SZ;

    short* Wt_attn = R1;
    short* Aout    = R1;
    short* Wt_proj = Qw;
    short* Xb      = (short*)d_out;            // d_out as bf16 scratch until proj

    convx<<<dim3(2048), 256, 0, stream>>>(x, Xb);
    convt<<<dim3(48, 16), 256, 0, stream>>>(W_attn, Wt_attn, 1024, 3072);
    qkv_gemm<<<dim3(256), 512, 0, stream>>>(Xb, Wt_attn, b_attn, Qw, Kw, Vt);
    attn_v6<<<dim3(2048), 64, 0, stream>>>(Qw, Kw, Vt, Aout);
    convt<<<dim3(16, 16), 256, 0, stream>>>(W_proj, Wt_proj, 1024, 1024);
    proj_gemm<<<dim3(16, 32), 256, 0, stream>>>(Aout, Wt_proj, b_proj, out);
}